// Round 1
// 418.806 us; speedup vs baseline: 1.1926x; 1.1926x over previous
//
#include <hip/hip_runtime.h>
#include <hip/hip_bf16.h>
#include <math.h>

constexpr int B = 2, L = 1024, D = 1024, H = 16, DK = 64;
constexpr int M = B * L;           // 2048 rows
constexpr int DD = D * D;

typedef __attribute__((ext_vector_type(8))) short bf16x8;
typedef __attribute__((ext_vector_type(4))) float f32x4;

__device__ inline unsigned short f2bf(float f) {
    __hip_bfloat16 h = __float2bfloat16(f);
    return __builtin_bit_cast(unsigned short, h);
}

// async global->LDS, 16B per lane; LDS dest = base + lane*16 (wave-uniform base)
__device__ inline void glds16(const void* g, void* l) {
    __builtin_amdgcn_global_load_lds((const __attribute__((address_space(1))) void*)g,
                                     (__attribute__((address_space(3))) void*)l,
                                     16, 0, 0);
}

// ---------------- LayerNorm: qn16 = LN(query) bf16, q16 = bf16(query) -------
__global__ __launch_bounds__(256) void ln2_kernel(const float* __restrict__ x,
                                                  const float* __restrict__ gamma,
                                                  const float* __restrict__ beta,
                                                  unsigned short* __restrict__ qn16,
                                                  unsigned short* __restrict__ q16) {
    int row = blockIdx.x;
    int t = threadIdx.x;
    const float4 v = ((const float4*)(x + (size_t)row * D))[t];
    float s  = v.x + v.y + v.z + v.w;
    float sq = v.x*v.x + v.y*v.y + v.z*v.z + v.w*v.w;
    #pragma unroll
    for (int m = 32; m >= 1; m >>= 1) {
        s  += __shfl_xor(s, m, 64);
        sq += __shfl_xor(sq, m, 64);
    }
    __shared__ float rs[4], rq[4];
    int wid = t >> 6;
    if ((t & 63) == 0) { rs[wid] = s; rq[wid] = sq; }
    __syncthreads();
    s  = rs[0] + rs[1] + rs[2] + rs[3];
    sq = rq[0] + rq[1] + rq[2] + rq[3];
    float mean = s * (1.0f / D);
    float var  = sq * (1.0f / D) - mean * mean;
    float rstd = rsqrtf(var + 1e-6f);
    float4 g  = ((const float4*)gamma)[t];
    float4 bb = ((const float4*)beta)[t];
    ushort4 on, oq;
    on.x = f2bf((v.x - mean) * rstd * g.x + bb.x);
    on.y = f2bf((v.y - mean) * rstd * g.y + bb.y);
    on.z = f2bf((v.z - mean) * rstd * g.z + bb.z);
    on.w = f2bf((v.w - mean) * rstd * g.w + bb.w);
    oq.x = f2bf(v.x); oq.y = f2bf(v.y); oq.z = f2bf(v.z); oq.w = f2bf(v.w);
    ((ushort4*)(qn16 + (size_t)row * D))[t] = on;
    ((ushort4*)(q16  + (size_t)row * D))[t] = oq;
}

// ---------------- weight cast: 4 x (D,D) fp32 -> bf16 ----------------------
__global__ __launch_bounds__(256) void wconv_kernel(const float* __restrict__ Wq,
                                                    const float* __restrict__ Wk,
                                                    const float* __restrict__ Wv,
                                                    const float* __restrict__ Wo,
                                                    unsigned short* __restrict__ out) {
    const float* src = (blockIdx.y == 0) ? Wq : (blockIdx.y == 1) ? Wk
                       : (blockIdx.y == 2) ? Wv : Wo;
    size_t i = (size_t)blockIdx.x * 256 + threadIdx.x;
    float4 v = ((const float4*)src)[i];
    ushort4 o;
    o.x = f2bf(v.x); o.y = f2bf(v.y); o.z = f2bf(v.z); o.w = f2bf(v.w);
    ((ushort4*)(out + (size_t)blockIdx.y * DD))[i] = o;
}

// ---------------- lsm: fused lexical mask + hard mask -> additive bias -----
__global__ __launch_bounds__(256) void lsm_kernel(const float* __restrict__ lex,
                                                  const int* __restrict__ mask,
                                                  float* __restrict__ lsm) {
    int i = blockIdx.x * 256 + threadIdx.x;      // B*L = 2048
    lsm[i] = mask[i] ? lex[i] : -1e30f;
}

// ---------------- fused QKV GEMM: 128x128 tile, BK=64, global_load_lds ------
// Swizzled LDS: phys chunk = logical chunk ^ (row&7); rows of 64 shorts, no pad.
__global__ __launch_bounds__(256) void gemm_qkv(
        const unsigned short* __restrict__ qn16, const unsigned short* __restrict__ q16,
        const unsigned short* __restrict__ W,
        const float* __restrict__ bq, const float* __restrict__ bk,
        const float* __restrict__ bv,
        unsigned short* __restrict__ Qm, unsigned short* __restrict__ Km,
        unsigned short* __restrict__ Vm) {
    __shared__ __align__(16) unsigned short As[128 * 64];
    __shared__ __align__(16) unsigned short Ws[128 * 64];
    int t = threadIdx.x, lane = t & 63, w = t >> 6;
    int quad = lane >> 4, l15 = lane & 15;
    int nt = blockIdx.x;                 // 0..23
    int bm = blockIdx.y * 128;
    const unsigned short* A = (nt < 8) ? qn16 : q16;
    const float* bias = (nt < 8) ? bq : ((nt < 16) ? bk : bv);
    unsigned short* Cout = (nt < 8) ? Qm : ((nt < 16) ? Km : Vm);
    int bn_local = (nt & 7) * 128;
    int wm = (w >> 1) * 64, wn = (w & 1) * 64;
    f32x4 acc[4][4] = {};
    for (int k0 = 0; k0 < D; k0 += 64) {
        __syncthreads();
        const unsigned short* ap = A + (size_t)(bm + w * 32) * D + k0;
        const unsigned short* wp = W + (size_t)(nt * 128 + w * 32) * D + k0;
        #pragma unroll
        for (int i = 0; i < 4; i++) {
            int c = i * 64 + lane;
            int r = c >> 3, g = (c & 7) ^ (r & 7);
            glds16(ap + (size_t)r * D + g * 8, &As[w * 2048 + i * 512]);
            glds16(wp + (size_t)r * D + g * 8, &Ws[w * 2048 + i * 512]);
        }
        __syncthreads();
        #pragma unroll
        for (int k2 = 0; k2 < 2; k2++) {
            bf16x8 av[4], bw[4];
            #pragma unroll
            for (int i = 0; i < 4; i++) {
                int r = wm + i * 16 + l15;
                av[i] = *(const bf16x8*)&As[r * 64 + (((quad + 4 * k2) ^ (r & 7)) * 8)];
            }
            #pragma unroll
            for (int j = 0; j < 4; j++) {
                int r = wn + j * 16 + l15;
                bw[j] = *(const bf16x8*)&Ws[r * 64 + (((quad + 4 * k2) ^ (r & 7)) * 8)];
            }
            #pragma unroll
            for (int i = 0; i < 4; i++)
                #pragma unroll
                for (int j = 0; j < 4; j++)
                    acc[i][j] = __builtin_amdgcn_mfma_f32_16x16x32_bf16(av[i], bw[j], acc[i][j], 0, 0, 0);
        }
    }
    #pragma unroll
    for (int j = 0; j < 4; j++) {
        int col = bn_local + wn + j * 16 + l15;
        float bcol = bias[col];
        #pragma unroll
        for (int i = 0; i < 4; i++)
            #pragma unroll
            for (int rg = 0; rg < 4; rg++) {
                int row = bm + wm + i * 16 + quad * 4 + rg;
                Cout[(size_t)row * D + col] = f2bf(acc[i][j][rg] + bcol);
            }
    }
}

// ---------------- V transpose: Vm [b,s,h*64+d] -> Vt [bh][d][s] ------------
__global__ __launch_bounds__(256) void vtrans_kernel(const unsigned short* __restrict__ Vm,
                                                     unsigned short* __restrict__ Vt) {
    __shared__ unsigned short sb[128 * 66];
    int t = threadIdx.x;
    int z = blockIdx.y;
    int b = z >> 4, h = z & 15;
    int s0 = blockIdx.x * 128;
    size_t base = (size_t)b * L * D + (size_t)h * 64;
    #pragma unroll
    for (int i = 0; i < 4; i++) {
        int idx = t + 256 * i;
        int r = idx >> 3, c8 = idx & 7;
        uint4 vv = *(const uint4*)&Vm[base + (size_t)(s0 + r) * D + c8 * 8];
        unsigned int* sp = (unsigned int*)&sb[r * 66 + c8 * 8];
        sp[0] = vv.x; sp[1] = vv.y; sp[2] = vv.z; sp[3] = vv.w;
    }
    __syncthreads();
    #pragma unroll
    for (int i = 0; i < 4; i++) {
        int idx = t + 256 * i;
        int d = idx >> 4, sc = idx & 15;
        unsigned short tmp[8];
        #pragma unroll
        for (int j = 0; j < 8; j++) tmp[j] = sb[(sc * 8 + j) * 66 + d];
        *(uint4*)&Vt[((size_t)z * 64 + d) * L + s0 + sc * 8] = *(uint4*)tmp;
    }
}

// ---------------- attention: S^T = K Q^T, bias streaming fused into stages --
// Block: (b,h) x 16 queries. Lane holds S^T[s][q = q0+l15].
// Per stage st (128 keys): issue K glds16 + this stage's bias float4 loads,
// one barrier drains both, MFMA, then bias-add with prefetched regs.
// launch_bounds(256,4): force <=128 VGPR -> 4 waves/SIMD (occupancy cliff).
__global__ __launch_bounds__(256, 4) void attn4_kernel(
        const unsigned short* __restrict__ Qm, const unsigned short* __restrict__ Km,
        const float* __restrict__ pos_bias, const float* __restrict__ postag,
        const float* __restrict__ lsm, float* __restrict__ attn_out) {
    __shared__ __align__(16) unsigned short q_sh[16][72];
    __shared__ __align__(16) unsigned short kv_sh[128 * 64];   // swizzled, no pad
    __shared__ float lsm_sh[1024];
    __shared__ float redA[16][4], redB[16][4];

    int t = threadIdx.x, lane = t & 63, w = t >> 6;
    int quad = lane >> 4, l15 = lane & 15;
    int qt = blockIdx.x & 63;
    int bh = blockIdx.x >> 6;
    int b = bh >> 4, h = bh & 15;
    int q0 = qt * 16;
    int q = q0 + l15;
    size_t base = (size_t)b * L * D + (size_t)h * DK;

    if (t < 128) {
        int r = t >> 3, c8 = t & 7;
        *(uint4*)&q_sh[r][c8 * 8] = *(const uint4*)&Qm[base + (size_t)(q0 + r) * D + c8 * 8];
    }
    ((float4*)lsm_sh)[t] = ((const float4*)(lsm + b * L))[t];
    __syncthreads();
    bf16x8 qb0 = *(const bf16x8*)&q_sh[l15][quad * 8];
    bf16x8 qb1 = *(const bf16x8*)&q_sh[l15][32 + quad * 8];

    const float* pbp = pos_bias + ((size_t)h * L + q) * L;
    const float* ptp = postag + ((size_t)bh * L + q) * L;

    f32x4 acc[16] = {};
    for (int st = 0; st < 8; st++) {
        __syncthreads();                               // kv_sh reuse guard
        const unsigned short* kp = Km + base + (size_t)(st * 128 + w * 32) * D;
        #pragma unroll
        for (int i = 0; i < 4; i++) {
            int c = i * 64 + lane;
            int r = c >> 3, g = (c & 7) ^ (r & 7);
            glds16(kp + (size_t)r * D + g * 8, &kv_sh[w * 2048 + i * 512]);
        }
        // bias prefetch for this stage's s-range (overlaps K load latency)
        int s_u0 = st * 128 + w * 16 + quad * 4;       // u=0 rows
        int s_u1 = s_u0 + 64;                          // u=1 rows
        float4 pb0 = *(const float4*)(pbp + s_u0);
        float4 pt0 = *(const float4*)(ptp + s_u0);
        float4 pb1 = *(const float4*)(pbp + s_u1);
        float4 pt1 = *(const float4*)(ptp + s_u1);
        __syncthreads();                               // K tile + bias regs ready
        #pragma unroll
        for (int u = 0; u < 2; u++) {
            int r = (u * 4 + w) * 16 + l15;            // s-row within stage
            bf16x8 ka0 = *(const bf16x8*)&kv_sh[r * 64 + ((quad ^ (r & 7)) * 8)];
            bf16x8 ka1 = *(const bf16x8*)&kv_sh[r * 64 + (((quad + 4) ^ (r & 7)) * 8)];
            int ti = 2 * st + u;
            acc[ti] = __builtin_amdgcn_mfma_f32_16x16x32_bf16(ka0, qb0, acc[ti], 0, 0, 0);
            acc[ti] = __builtin_amdgcn_mfma_f32_16x16x32_bf16(ka1, qb1, acc[ti], 0, 0, 0);
        }
        // bias add, consuming prefetched regs (acc for this stage is final)
        {
            int ti = 2 * st;
            float4 l0 = *(const float4*)&lsm_sh[s_u0];   // broadcast across l15
            acc[ti][0] = acc[ti][0] * 0.125f + (pb0.x + pt0.x + l0.x);
            acc[ti][1] = acc[ti][1] * 0.125f + (pb0.y + pt0.y + l0.y);
            acc[ti][2] = acc[ti][2] * 0.125f + (pb0.z + pt0.z + l0.z);
            acc[ti][3] = acc[ti][3] * 0.125f + (pb0.w + pt0.w + l0.w);
            ti = 2 * st + 1;
            float4 l1 = *(const float4*)&lsm_sh[s_u1];
            acc[ti][0] = acc[ti][0] * 0.125f + (pb1.x + pt1.x + l1.x);
            acc[ti][1] = acc[ti][1] * 0.125f + (pb1.y + pt1.y + l1.y);
            acc[ti][2] = acc[ti][2] * 0.125f + (pb1.z + pt1.z + l1.z);
            acc[ti][3] = acc[ti][3] * 0.125f + (pb1.w + pt1.w + l1.w);
        }
    }
    // ---- softmax over s: per-lane -> quads (shfl 16,32) -> waves (LDS) ----
    float mx = -1e30f;
    #pragma unroll
    for (int ti = 0; ti < 16; ti++)
        #pragma unroll
        for (int rg = 0; rg < 4; rg++) mx = fmaxf(mx, acc[ti][rg]);
    mx = fmaxf(mx, __shfl_xor(mx, 16, 64));
    mx = fmaxf(mx, __shfl_xor(mx, 32, 64));
    if (quad == 0) redA[l15][w] = mx;
    __syncthreads();
    mx = fmaxf(fmaxf(redA[l15][0], redA[l15][1]), fmaxf(redA[l15][2], redA[l15][3]));
    float sum = 0.f;
    #pragma unroll
    for (int ti = 0; ti < 16; ti++)
        #pragma unroll
        for (int rg = 0; rg < 4; rg++) {
            float e = __expf(acc[ti][rg] - mx);
            acc[ti][rg] = e;
            sum += e;
        }
    sum += __shfl_xor(sum, 16, 64);
    sum += __shfl_xor(sum, 32, 64);
    if (quad == 0) redB[l15][w] = sum;
    __syncthreads();
    float inv = 1.0f / (redB[l15][0] + redB[l15][1] + redB[l15][2] + redB[l15][3]);
    // ---- write attn (float4 along s) ----
    #pragma unroll
    for (int ti = 0; ti < 16; ti++) {
        int s0 = (ti >> 1) * 128 + (ti & 1) * 64 + w * 16 + quad * 4;
        float4 o;
        o.x = acc[ti][0] * inv; o.y = acc[ti][1] * inv;
        o.z = acc[ti][2] * inv; o.w = acc[ti][3] * inv;
        *(float4*)&attn_out[((size_t)bh * L + q) * L + s0] = o;
    }
}

// ---------------- PV GEMM: ctx[bh-tile] = attn(fp32) @ Vt^T, 64x64 tile ----
__global__ __launch_bounds__(256) void gemm_pv(
        const float* __restrict__ attnP, const unsigned short* __restrict__ Vt,
        unsigned short* __restrict__ ctx16) {
    __shared__ __align__(16) unsigned short As[64][72];        // padded (cvt path)
    __shared__ __align__(16) unsigned short Ws[64 * 64];       // swizzled glds
    int t = threadIdx.x, lane = t & 63, w = t >> 6;
    int quad = lane >> 4, l15 = lane & 15;
    int bm = blockIdx.x * 64, z = blockIdx.z;
    int wm = (w >> 1) * 32, wn = (w & 1) * 32;
    int ar = t >> 2, ac = (t & 3) * 16;
    f32x4 acc[2][2] = {};
    for (int k0 = 0; k0 < L; k0 += 64) {
        __syncthreads();
        const unsigned short* wp = Vt + ((size_t)z * 64 + w * 16) * L + k0;
        #pragma unroll
        for (int i = 0; i < 2; i++) {
            int c = i * 64 + lane;
            int r = c >> 3, g = (c & 7) ^ (r & 7);
            glds16(wp + (size_t)r * L + g * 8, &Ws[w * 1024 + i * 512]);
        }
        {   // A: fp32 -> bf16 staging (16 floats/thread)
            const float* ap = &attnP[((size_t)z * L + bm + ar) * L + k0 + ac];
            float4 f0 = *(const float4*)ap;
            float4 f1 = *(const float4*)(ap + 4);
            float4 f2 = *(const float4*)(ap + 8);
            float4 f3 = *(const float4*)(ap + 12);
            ushort4 u0, u1, u2, u3;
            u0.x = f2bf(f0.x); u0.y = f2bf(f0.y); u0.z = f2bf(f0.z); u0.w = f2bf(f0.w);
            u1.x = f2bf(f1.x); u1.y = f2bf(f1.y); u1.z = f2bf(f1.z); u1.w = f2bf(f1.w);
            u2.x = f2bf(f2.x); u2.y = f2bf(f2.y); u2.z = f2bf(f2.z); u2.w = f2bf(f2.w);
            u3.x = f2bf(f3.x); u3.y = f2bf(f3.y); u3.z = f2bf(f3.z); u3.w = f2bf(f3.w);
            *(ushort4*)&As[ar][ac]      = u0;
            *(ushort4*)&As[ar][ac + 4]  = u1;
            *(ushort4*)&As[ar][ac + 8]  = u2;
            *(ushort4*)&As[ar][ac + 12] = u3;
        }
        __syncthreads();
        #pragma unroll
        for (int k2 = 0; k2 < 2; k2++) {
            bf16x8 av[2], bw[2];
            #pragma unroll
            for (int i = 0; i < 2; i++)
                av[i] = *(const bf16x8*)&As[wm + i * 16 + l15][k2 * 32 + quad * 8];
            #pragma unroll
            for (int j = 0; j < 2; j++) {
                int r = wn + j * 16 + l15;
                bw[j] = *(const bf16x8*)&Ws[r * 64 + (((quad + 4 * k2) ^ (r & 7)) * 8)];
            }
            #pragma unroll
            for (int i = 0; i < 2; i++)
                #pragma unroll
                for (int j = 0; j < 2; j++)
                    acc[i][j] = __builtin_amdgcn_mfma_f32_16x16x32_bf16(av[i], bw[j], acc[i][j], 0, 0, 0);
        }
    }
    size_t coff = (size_t)(z >> 4) * L * D + (size_t)(z & 15) * 64;
    #pragma unroll
    for (int i = 0; i < 2; i++)
        #pragma unroll
        for (int j = 0; j < 2; j++)
            #pragma unroll
            for (int rg = 0; rg < 4; rg++) {
                int row = bm + wm + i * 16 + quad * 4 + rg;
                int col = wn + j * 16 + l15;
                ctx16[coff + (size_t)row * D + col] = f2bf(acc[i][j][rg]);
            }
}

// ---------------- out GEMM: out = ctx @ Wo^T + bo + query, 64x64 tile ------
__global__ __launch_bounds__(256) void gemm_out(
        const unsigned short* __restrict__ A, const unsigned short* __restrict__ W,
        const float* __restrict__ bias, const float* __restrict__ res,
        float* __restrict__ C) {
    __shared__ __align__(16) unsigned short As[64 * 64];
    __shared__ __align__(16) unsigned short Ws[64 * 64];
    int t = threadIdx.x, lane = t & 63, w = t >> 6;
    int quad = lane >> 4, l15 = lane & 15;
    int bm = blockIdx.x * 64, bn = blockIdx.y * 64;
    int wm = (w >> 1) * 32, wn = (w & 1) * 32;
    f32x4 acc[2][2] = {};
    for (int k0 = 0; k0 < D; k0 += 64) {
        __syncthreads();
        const unsigned short* ap = A + (size_t)(bm + w * 16) * D + k0;
        const unsigned short* wp = W + (size_t)(bn + w * 16) * D + k0;
        #pragma unroll
        for (int i = 0; i < 2; i++) {
            int c = i * 64 + lane;
            int r = c >> 3, g = (c & 7) ^ (r & 7);
            glds16(ap + (size_t)r * D + g * 8, &As[w * 1024 + i * 512]);
            glds16(wp + (size_t)r * D + g * 8, &Ws[w * 1024 + i * 512]);
        }
        __syncthreads();
        #pragma unroll
        for (int k2 = 0; k2 < 2; k2++) {
            bf16x8 av[2], bw[2];
            #pragma unroll
            for (int i = 0; i < 2; i++) {
                int r = wm + i * 16 + l15;
                av[i] = *(const bf16x8*)&As[r * 64 + (((quad + 4 * k2) ^ (r & 7)) * 8)];
            }
            #pragma unroll
            for (int j = 0; j < 2; j++) {
                int r = wn + j * 16 + l15;
                bw[j] = *(const bf16x8*)&Ws[r * 64 + (((quad + 4 * k2) ^ (r & 7)) * 8)];
            }
            #pragma unroll
            for (int i = 0; i < 2; i++)
                #pragma unroll
                for (int j = 0; j < 2; j++)
                    acc[i][j] = __builtin_amdgcn_mfma_f32_16x16x32_bf16(av[i], bw[j], acc[i][j], 0, 0, 0);
        }
    }
    #pragma unroll
    for (int j = 0; j < 2; j++) {
        int col = bn + wn + j * 16 + l15;
        float bcol = bias[col];
        #pragma unroll
        for (int i = 0; i < 2; i++)
            #pragma unroll
            for (int rg = 0; rg < 4; rg++) {
                int row = bm + wm + i * 16 + quad * 4 + rg;
                C[(size_t)row * D + col] = acc[i][j][rg] + bcol + res[(size_t)row * D + col];
            }
    }
}

extern "C" void kernel_launch(void* const* d_in, const int* in_sizes, int n_in,
                              void* d_out, int out_size, void* d_ws, size_t ws_size,
                              hipStream_t stream) {
    (void)in_sizes; (void)n_in; (void)out_size; (void)ws_size;
    const float* query  = (const float*)d_in[0];
    const float* pos_b  = (const float*)d_in[1];
    const float* postag = (const float*)d_in[2];
    const float* lex    = (const float*)d_in[3];
    const int*   mask   = (const int*)d_in[4];
    const float* Wq = (const float*)d_in[5];
    const float* bq = (const float*)d_in[6];
    const float* Wk = (const float*)d_in[7];
    const float* bk = (const float*)d_in[8];
    const float* Wv = (const float*)d_in[9];
    const float* bv = (const float*)d_in[10];
    const float* Wo = (const float*)d_in[11];
    const float* bo = (const float*)d_in[12];
    const float* gamma = (const float*)d_in[13];
    const float* beta  = (const float*)d_in[14];

    float* out  = (float*)d_out;                 // (B,L,D)
    float* attn = out + (size_t)B * L * D;       // (B,H,L,L)

    unsigned short* ws16 = (unsigned short*)d_ws;
    const size_t NE = (size_t)M * D;
    unsigned short* qn16  = ws16;
    unsigned short* q16   = ws16 + NE;
    unsigned short* W16   = ws16 + 2 * NE;       // 4*DD
    unsigned short* Qm16  = W16 + 4 * (size_t)DD;
    unsigned short* Km16  = Qm16 + NE;
    unsigned short* Vm16  = Km16 + NE;
    unsigned short* Vt16  = Vm16 + NE;           // [32][64][1024]
    unsigned short* ctx16 = Vt16 + NE;
    float* lsm = (float*)(ctx16 + NE);           // (B,L) fused lex+mask

    ln2_kernel<<<M, 256, 0, stream>>>(query, gamma, beta, qn16, q16);
    wconv_kernel<<<dim3(DD / 1024, 4), 256, 0, stream>>>(Wq, Wk, Wv, Wo, W16);
    lsm_kernel<<<M / 256, 256, 0, stream>>>(lex, mask, lsm);
    gemm_qkv<<<dim3(24, 16), 256, 0, stream>>>(qn16, q16, W16, bq, bk, bv,
                                               Qm16, Km16, Vm16);
    vtrans_kernel<<<dim3(8, 32), 256, 0, stream>>>(Vm16, Vt16);
    attn4_kernel<<<B * H * (L / 16), 256, 0, stream>>>(Qm16, Km16, pos_b, postag,
                                                       lsm, attn);
    gemm_pv<<<dim3(16, 1, 32), 256, 0, stream>>>(attn, Vt16, ctx16);
    gemm_out<<<dim3(32, 16), 256, 0, stream>>>(ctx16, W16 + 3 * (size_t)DD, bo, query, out);
}

// Round 2
// 408.100 us; speedup vs baseline: 1.2239x; 1.0262x over previous
//
#include <hip/hip_runtime.h>
#include <hip/hip_bf16.h>
#include <math.h>

constexpr int B = 2, L = 1024, D = 1024, H = 16, DK = 64;
constexpr int M = B * L;           // 2048 rows
constexpr int DD = D * D;

typedef __attribute__((ext_vector_type(8))) short bf16x8;
typedef __attribute__((ext_vector_type(4))) float f32x4;

__device__ inline unsigned short f2bf(float f) {
    __hip_bfloat16 h = __float2bfloat16(f);
    return __builtin_bit_cast(unsigned short, h);
}

// async global->LDS, 16B per lane; LDS dest = base + lane*16 (wave-uniform base)
__device__ inline void glds16(const void* g, void* l) {
    __builtin_amdgcn_global_load_lds((const __attribute__((address_space(1))) void*)g,
                                     (__attribute__((address_space(3))) void*)l,
                                     16, 0, 0);
}

// ---------------- LayerNorm: qn16 = LN(query) bf16, q16 = bf16(query) -------
__global__ __launch_bounds__(256) void ln2_kernel(const float* __restrict__ x,
                                                  const float* __restrict__ gamma,
                                                  const float* __restrict__ beta,
                                                  unsigned short* __restrict__ qn16,
                                                  unsigned short* __restrict__ q16) {
    int row = blockIdx.x;
    int t = threadIdx.x;
    const float4 v = ((const float4*)(x + (size_t)row * D))[t];
    float s  = v.x + v.y + v.z + v.w;
    float sq = v.x*v.x + v.y*v.y + v.z*v.z + v.w*v.w;
    #pragma unroll
    for (int m = 32; m >= 1; m >>= 1) {
        s  += __shfl_xor(s, m, 64);
        sq += __shfl_xor(sq, m, 64);
    }
    __shared__ float rs[4], rq[4];
    int wid = t >> 6;
    if ((t & 63) == 0) { rs[wid] = s; rq[wid] = sq; }
    __syncthreads();
    s  = rs[0] + rs[1] + rs[2] + rs[3];
    sq = rq[0] + rq[1] + rq[2] + rq[3];
    float mean = s * (1.0f / D);
    float var  = sq * (1.0f / D) - mean * mean;
    float rstd = rsqrtf(var + 1e-6f);
    float4 g  = ((const float4*)gamma)[t];
    float4 bb = ((const float4*)beta)[t];
    ushort4 on, oq;
    on.x = f2bf((v.x - mean) * rstd * g.x + bb.x);
    on.y = f2bf((v.y - mean) * rstd * g.y + bb.y);
    on.z = f2bf((v.z - mean) * rstd * g.z + bb.z);
    on.w = f2bf((v.w - mean) * rstd * g.w + bb.w);
    oq.x = f2bf(v.x); oq.y = f2bf(v.y); oq.z = f2bf(v.z); oq.w = f2bf(v.w);
    ((ushort4*)(qn16 + (size_t)row * D))[t] = on;
    ((ushort4*)(q16  + (size_t)row * D))[t] = oq;
}

// ---------------- weight cast: 4 x (D,D) fp32 -> bf16 ----------------------
__global__ __launch_bounds__(256) void wconv_kernel(const float* __restrict__ Wq,
                                                    const float* __restrict__ Wk,
                                                    const float* __restrict__ Wv,
                                                    const float* __restrict__ Wo,
                                                    unsigned short* __restrict__ out) {
    const float* src = (blockIdx.y == 0) ? Wq : (blockIdx.y == 1) ? Wk
                       : (blockIdx.y == 2) ? Wv : Wo;
    size_t i = (size_t)blockIdx.x * 256 + threadIdx.x;
    float4 v = ((const float4*)src)[i];
    ushort4 o;
    o.x = f2bf(v.x); o.y = f2bf(v.y); o.z = f2bf(v.z); o.w = f2bf(v.w);
    ((ushort4*)(out + (size_t)blockIdx.y * DD))[i] = o;
}

// ---------------- lsm: fused lexical mask + hard mask -> additive bias -----
__global__ __launch_bounds__(256) void lsm_kernel(const float* __restrict__ lex,
                                                  const int* __restrict__ mask,
                                                  float* __restrict__ lsm) {
    int i = blockIdx.x * 256 + threadIdx.x;      // B*L = 2048
    lsm[i] = mask[i] ? lex[i] : -1e30f;
}

// ---------------- fused QKV GEMM: 128x128 tile, BK=64, global_load_lds ------
// Swizzled LDS: phys chunk = logical chunk ^ (row&7); rows of 64 shorts, no pad.
__global__ __launch_bounds__(256) void gemm_qkv(
        const unsigned short* __restrict__ qn16, const unsigned short* __restrict__ q16,
        const unsigned short* __restrict__ W,
        const float* __restrict__ bq, const float* __restrict__ bk,
        const float* __restrict__ bv,
        unsigned short* __restrict__ Qm, unsigned short* __restrict__ Km,
        unsigned short* __restrict__ Vm) {
    __shared__ __align__(16) unsigned short As[128 * 64];
    __shared__ __align__(16) unsigned short Ws[128 * 64];
    int t = threadIdx.x, lane = t & 63, w = t >> 6;
    int quad = lane >> 4, l15 = lane & 15;
    int nt = blockIdx.x;                 // 0..23
    int bm = blockIdx.y * 128;
    const unsigned short* A = (nt < 8) ? qn16 : q16;
    const float* bias = (nt < 8) ? bq : ((nt < 16) ? bk : bv);
    unsigned short* Cout = (nt < 8) ? Qm : ((nt < 16) ? Km : Vm);
    int bn_local = (nt & 7) * 128;
    int wm = (w >> 1) * 64, wn = (w & 1) * 64;
    f32x4 acc[4][4] = {};
    for (int k0 = 0; k0 < D; k0 += 64) {
        __syncthreads();
        const unsigned short* ap = A + (size_t)(bm + w * 32) * D + k0;
        const unsigned short* wp = W + (size_t)(nt * 128 + w * 32) * D + k0;
        #pragma unroll
        for (int i = 0; i < 4; i++) {
            int c = i * 64 + lane;
            int r = c >> 3, g = (c & 7) ^ (r & 7);
            glds16(ap + (size_t)r * D + g * 8, &As[w * 2048 + i * 512]);
            glds16(wp + (size_t)r * D + g * 8, &Ws[w * 2048 + i * 512]);
        }
        __syncthreads();
        #pragma unroll
        for (int k2 = 0; k2 < 2; k2++) {
            bf16x8 av[4], bw[4];
            #pragma unroll
            for (int i = 0; i < 4; i++) {
                int r = wm + i * 16 + l15;
                av[i] = *(const bf16x8*)&As[r * 64 + (((quad + 4 * k2) ^ (r & 7)) * 8)];
            }
            #pragma unroll
            for (int j = 0; j < 4; j++) {
                int r = wn + j * 16 + l15;
                bw[j] = *(const bf16x8*)&Ws[r * 64 + (((quad + 4 * k2) ^ (r & 7)) * 8)];
            }
            #pragma unroll
            for (int i = 0; i < 4; i++)
                #pragma unroll
                for (int j = 0; j < 4; j++)
                    acc[i][j] = __builtin_amdgcn_mfma_f32_16x16x32_bf16(av[i], bw[j], acc[i][j], 0, 0, 0);
        }
    }
    #pragma unroll
    for (int j = 0; j < 4; j++) {
        int col = bn_local + wn + j * 16 + l15;
        float bcol = bias[col];
        #pragma unroll
        for (int i = 0; i < 4; i++)
            #pragma unroll
            for (int rg = 0; rg < 4; rg++) {
                int row = bm + wm + i * 16 + quad * 4 + rg;
                Cout[(size_t)row * D + col] = f2bf(acc[i][j][rg] + bcol);
            }
    }
}

// ---------------- V transpose: Vm [b,s,h*64+d] -> Vt [bh][d][s] ------------
__global__ __launch_bounds__(256) void vtrans_kernel(const unsigned short* __restrict__ Vm,
                                                     unsigned short* __restrict__ Vt) {
    __shared__ unsigned short sb[128 * 66];
    int t = threadIdx.x;
    int z = blockIdx.y;
    int b = z >> 4, h = z & 15;
    int s0 = blockIdx.x * 128;
    size_t base = (size_t)b * L * D + (size_t)h * 64;
    #pragma unroll
    for (int i = 0; i < 4; i++) {
        int idx = t + 256 * i;
        int r = idx >> 3, c8 = idx & 7;
        uint4 vv = *(const uint4*)&Vm[base + (size_t)(s0 + r) * D + c8 * 8];
        unsigned int* sp = (unsigned int*)&sb[r * 66 + c8 * 8];
        sp[0] = vv.x; sp[1] = vv.y; sp[2] = vv.z; sp[3] = vv.w;
    }
    __syncthreads();
    #pragma unroll
    for (int i = 0; i < 4; i++) {
        int idx = t + 256 * i;
        int d = idx >> 4, sc = idx & 15;
        unsigned short tmp[8];
        #pragma unroll
        for (int j = 0; j < 8; j++) tmp[j] = sb[(sc * 8 + j) * 66 + d];
        *(uint4*)&Vt[((size_t)z * 64 + d) * L + s0 + sc * 8] = *(uint4*)tmp;
    }
}

// ---------------- fused attention + PV --------------------------------------
// Phase 1: S^T = K Q^T with bias streaming fused into 8 K-stages.
// Softmax in-register; attn written fp32 (mandatory output), acc normalized.
// Phase 2: ctx = P V via 8 V-stages; P chunk staged bf16 in p_sh, wave w owns
// d-tile w (no cross-wave reduction). kv_sh reused as V tile [64 d][128 s].
__global__ __launch_bounds__(256, 4) void attn_pv_kernel(
        const unsigned short* __restrict__ Qm, const unsigned short* __restrict__ Km,
        const unsigned short* __restrict__ Vt,
        const float* __restrict__ pos_bias, const float* __restrict__ postag,
        const float* __restrict__ lsm, float* __restrict__ attn_out,
        unsigned short* __restrict__ ctx16) {
    __shared__ __align__(16) unsigned short q_sh[16][72];
    __shared__ __align__(16) unsigned short kv_sh[128 * 64];   // K stages / V [64][128]
    __shared__ __align__(16) unsigned short p_sh[16][136];     // P chunk, padded
    __shared__ float lsm_sh[1024];
    __shared__ float redA[16][4], redB[16][4];

    int t = threadIdx.x, lane = t & 63, w = t >> 6;
    int quad = lane >> 4, l15 = lane & 15;
    int qt = blockIdx.x & 63;
    int bh = blockIdx.x >> 6;
    int b = bh >> 4, h = bh & 15;
    int q0 = qt * 16;
    int q = q0 + l15;
    size_t base = (size_t)b * L * D + (size_t)h * DK;

    if (t < 128) {
        int r = t >> 3, c8 = t & 7;
        *(uint4*)&q_sh[r][c8 * 8] = *(const uint4*)&Qm[base + (size_t)(q0 + r) * D + c8 * 8];
    }
    ((float4*)lsm_sh)[t] = ((const float4*)(lsm + b * L))[t];
    __syncthreads();
    bf16x8 qb0 = *(const bf16x8*)&q_sh[l15][quad * 8];
    bf16x8 qb1 = *(const bf16x8*)&q_sh[l15][32 + quad * 8];

    const float* pbp = pos_bias + ((size_t)h * L + q) * L;
    const float* ptp = postag + ((size_t)bh * L + q) * L;

    f32x4 acc[16] = {};
    // ---- Phase 1: S^T over 8 K-stages, bias fused -------------------------
    for (int st = 0; st < 8; st++) {
        __syncthreads();                               // kv_sh reuse guard
        const unsigned short* kp = Km + base + (size_t)(st * 128 + w * 32) * D;
        #pragma unroll
        for (int i = 0; i < 4; i++) {
            int c = i * 64 + lane;
            int r = c >> 3, g = (c & 7) ^ (r & 7);
            glds16(kp + (size_t)r * D + g * 8, &kv_sh[w * 2048 + i * 512]);
        }
        int s_u0 = st * 128 + w * 16 + quad * 4;
        int s_u1 = s_u0 + 64;
        float4 pb0 = *(const float4*)(pbp + s_u0);
        float4 pt0 = *(const float4*)(ptp + s_u0);
        float4 pb1 = *(const float4*)(pbp + s_u1);
        float4 pt1 = *(const float4*)(ptp + s_u1);
        __syncthreads();                               // K tile + bias regs ready
        #pragma unroll
        for (int u = 0; u < 2; u++) {
            int r = (u * 4 + w) * 16 + l15;
            bf16x8 ka0 = *(const bf16x8*)&kv_sh[r * 64 + ((quad ^ (r & 7)) * 8)];
            bf16x8 ka1 = *(const bf16x8*)&kv_sh[r * 64 + (((quad + 4) ^ (r & 7)) * 8)];
            int ti = 2 * st + u;
            acc[ti] = __builtin_amdgcn_mfma_f32_16x16x32_bf16(ka0, qb0, acc[ti], 0, 0, 0);
            acc[ti] = __builtin_amdgcn_mfma_f32_16x16x32_bf16(ka1, qb1, acc[ti], 0, 0, 0);
        }
        {
            int ti = 2 * st;
            float4 l0 = *(const float4*)&lsm_sh[s_u0];
            acc[ti][0] = acc[ti][0] * 0.125f + (pb0.x + pt0.x + l0.x);
            acc[ti][1] = acc[ti][1] * 0.125f + (pb0.y + pt0.y + l0.y);
            acc[ti][2] = acc[ti][2] * 0.125f + (pb0.z + pt0.z + l0.z);
            acc[ti][3] = acc[ti][3] * 0.125f + (pb0.w + pt0.w + l0.w);
            ti = 2 * st + 1;
            float4 l1 = *(const float4*)&lsm_sh[s_u1];
            acc[ti][0] = acc[ti][0] * 0.125f + (pb1.x + pt1.x + l1.x);
            acc[ti][1] = acc[ti][1] * 0.125f + (pb1.y + pt1.y + l1.y);
            acc[ti][2] = acc[ti][2] * 0.125f + (pb1.z + pt1.z + l1.z);
            acc[ti][3] = acc[ti][3] * 0.125f + (pb1.w + pt1.w + l1.w);
        }
    }
    // ---- softmax over s: per-lane -> quads (shfl 16,32) -> waves (LDS) ----
    float mx = -1e30f;
    #pragma unroll
    for (int ti = 0; ti < 16; ti++)
        #pragma unroll
        for (int rg = 0; rg < 4; rg++) mx = fmaxf(mx, acc[ti][rg]);
    mx = fmaxf(mx, __shfl_xor(mx, 16, 64));
    mx = fmaxf(mx, __shfl_xor(mx, 32, 64));
    if (quad == 0) redA[l15][w] = mx;
    __syncthreads();
    mx = fmaxf(fmaxf(redA[l15][0], redA[l15][1]), fmaxf(redA[l15][2], redA[l15][3]));
    float sum = 0.f;
    #pragma unroll
    for (int ti = 0; ti < 16; ti++)
        #pragma unroll
        for (int rg = 0; rg < 4; rg++) {
            float e = __expf(acc[ti][rg] - mx);
            acc[ti][rg] = e;
            sum += e;
        }
    sum += __shfl_xor(sum, 16, 64);
    sum += __shfl_xor(sum, 32, 64);
    if (quad == 0) redB[l15][w] = sum;
    __syncthreads();
    float inv = 1.0f / (redB[l15][0] + redB[l15][1] + redB[l15][2] + redB[l15][3]);
    // ---- write attn (float4 along s); keep normalized P in acc ------------
    #pragma unroll
    for (int ti = 0; ti < 16; ti++) {
        int s0 = (ti >> 1) * 128 + (ti & 1) * 64 + w * 16 + quad * 4;
        float4 o;
        o.x = acc[ti][0] * inv; o.y = acc[ti][1] * inv;
        o.z = acc[ti][2] * inv; o.w = acc[ti][3] * inv;
        acc[ti][0] = o.x; acc[ti][1] = o.y; acc[ti][2] = o.z; acc[ti][3] = o.w;
        *(float4*)&attn_out[((size_t)bh * L + q) * L + s0] = o;
    }
    // ---- Phase 2: ctx = P V over 8 V-stages; wave w owns d-tile w ---------
    f32x4 cacc = {};
    const unsigned short* vp = Vt + (size_t)bh * 64 * L;
    for (int st = 0; st < 8; st++) {
        __syncthreads();                               // kv_sh/p_sh reuse guard
        #pragma unroll
        for (int i = 0; i < 4; i++) {
            int r = w * 16 + i * 4 + (lane >> 4);
            int g = (lane & 15) ^ (r & 7);
            glds16(vp + (size_t)r * L + st * 128 + g * 8, &kv_sh[w * 2048 + i * 512]);
        }
        #pragma unroll
        for (int u = 0; u < 2; u++) {
            f32x4 p = acc[2 * st + u];
            ushort4 pu;
            pu.x = f2bf(p[0]); pu.y = f2bf(p[1]); pu.z = f2bf(p[2]); pu.w = f2bf(p[3]);
            *(ushort4*)&p_sh[l15][u * 64 + w * 16 + quad * 4] = pu;
        }
        __syncthreads();                               // V tile + P chunk ready
        int rv = w * 16 + l15;
        #pragma unroll
        for (int kk = 0; kk < 4; kk++) {
            bf16x8 vf = *(const bf16x8*)&kv_sh[rv * 128 + (((kk * 4 + quad) ^ (rv & 7)) * 8)];
            bf16x8 pf = *(const bf16x8*)&p_sh[l15][kk * 32 + quad * 8];
            cacc = __builtin_amdgcn_mfma_f32_16x16x32_bf16(pf, vf, cacc, 0, 0, 0);
        }
    }
    // ctx[d = w*16+l15][q = quad*4+rg] -> ctx16[(b*L + q0 + q)*D + h*64 + d]
    size_t cbase = ((size_t)b * L + q0) * D + (size_t)h * 64 + w * 16 + l15;
    #pragma unroll
    for (int rg = 0; rg < 4; rg++)
        ctx16[cbase + (size_t)(quad * 4 + rg) * D] = f2bf(cacc[rg]);
}

// ---------------- out GEMM: out = ctx @ Wo^T + bo + query, 64x64 tile ------
__global__ __launch_bounds__(256) void gemm_out(
        const unsigned short* __restrict__ A, const unsigned short* __restrict__ W,
        const float* __restrict__ bias, const float* __restrict__ res,
        float* __restrict__ C) {
    __shared__ __align__(16) unsigned short As[64 * 64];
    __shared__ __align__(16) unsigned short Ws[64 * 64];
    int t = threadIdx.x, lane = t & 63, w = t >> 6;
    int quad = lane >> 4, l15 = lane & 15;
    int bm = blockIdx.x * 64, bn = blockIdx.y * 64;
    int wm = (w >> 1) * 32, wn = (w & 1) * 32;
    f32x4 acc[2][2] = {};
    for (int k0 = 0; k0 < D; k0 += 64) {
        __syncthreads();
        const unsigned short* ap = A + (size_t)(bm + w * 16) * D + k0;
        const unsigned short* wp = W + (size_t)(bn + w * 16) * D + k0;
        #pragma unroll
        for (int i = 0; i < 2; i++) {
            int c = i * 64 + lane;
            int r = c >> 3, g = (c & 7) ^ (r & 7);
            glds16(ap + (size_t)r * D + g * 8, &As[w * 1024 + i * 512]);
            glds16(wp + (size_t)r * D + g * 8, &Ws[w * 1024 + i * 512]);
        }
        __syncthreads();
        #pragma unroll
        for (int k2 = 0; k2 < 2; k2++) {
            bf16x8 av[2], bw[2];
            #pragma unroll
            for (int i = 0; i < 2; i++) {
                int r = wm + i * 16 + l15;
                av[i] = *(const bf16x8*)&As[r * 64 + (((quad + 4 * k2) ^ (r & 7)) * 8)];
            }
            #pragma unroll
            for (int j = 0; j < 2; j++) {
                int r = wn + j * 16 + l15;
                bw[j] = *(const bf16x8*)&Ws[r * 64 + (((quad + 4 * k2) ^ (r & 7)) * 8)];
            }
            #pragma unroll
            for (int i = 0; i < 2; i++)
                #pragma unroll
                for (int j = 0; j < 2; j++)
                    acc[i][j] = __builtin_amdgcn_mfma_f32_16x16x32_bf16(av[i], bw[j], acc[i][j], 0, 0, 0);
        }
    }
    #pragma unroll
    for (int j = 0; j < 2; j++) {
        int col = bn + wn + j * 16 + l15;
        float bcol = bias[col];
        #pragma unroll
        for (int i = 0; i < 2; i++)
            #pragma unroll
            for (int rg = 0; rg < 4; rg++) {
                int row = bm + wm + i * 16 + quad * 4 + rg;
                C[(size_t)row * D + col] = acc[i][j][rg] + bcol + res[(size_t)row * D + col];
            }
    }
}

extern "C" void kernel_launch(void* const* d_in, const int* in_sizes, int n_in,
                              void* d_out, int out_size, void* d_ws, size_t ws_size,
                              hipStream_t stream) {
    (void)in_sizes; (void)n_in; (void)out_size; (void)ws_size;
    const float* query  = (const float*)d_in[0];
    const float* pos_b  = (const float*)d_in[1];
    const float* postag = (const float*)d_in[2];
    const float* lex    = (const float*)d_in[3];
    const int*   mask   = (const int*)d_in[4];
    const float* Wq = (const float*)d_in[5];
    const float* bq = (const float*)d_in[6];
    const float* Wk = (const float*)d_in[7];
    const float* bk = (const float*)d_in[8];
    const float* Wv = (const float*)d_in[9];
    const float* bv = (const float*)d_in[10];
    const float* Wo = (const float*)d_in[11];
    const float* bo = (const float*)d_in[12];
    const float* gamma = (const float*)d_in[13];
    const float* beta  = (const float*)d_in[14];

    float* out  = (float*)d_out;                 // (B,L,D)
    float* attn = out + (size_t)B * L * D;       // (B,H,L,L)

    unsigned short* ws16 = (unsigned short*)d_ws;
    const size_t NE = (size_t)M * D;
    unsigned short* qn16  = ws16;
    unsigned short* q16   = ws16 + NE;
    unsigned short* W16   = ws16 + 2 * NE;       // 4*DD
    unsigned short* Qm16  = W16 + 4 * (size_t)DD;
    unsigned short* Km16  = Qm16 + NE;
    unsigned short* Vm16  = Km16 + NE;
    unsigned short* Vt16  = Vm16 + NE;           // [32][64][1024]
    unsigned short* ctx16 = Vt16 + NE;
    float* lsm = (float*)(ctx16 + NE);           // (B,L) fused lex+mask

    ln2_kernel<<<M, 256, 0, stream>>>(query, gamma, beta, qn16, q16);
    wconv_kernel<<<dim3(DD / 1024, 4), 256, 0, stream>>>(Wq, Wk, Wv, Wo, W16);
    lsm_kernel<<<M / 256, 256, 0, stream>>>(lex, mask, lsm);
    gemm_qkv<<<dim3(24, 16), 256, 0, stream>>>(qn16, q16, W16, bq, bk, bv,
                                               Qm16, Km16, Vm16);
    vtrans_kernel<<<dim3(8, 32), 256, 0, stream>>>(Vm16, Vt16);
    attn_pv_kernel<<<B * H * (L / 16), 256, 0, stream>>>(Qm16, Km16, Vt16,
                                                         pos_b, postag, lsm,
                                                         attn, ctx16);
    gemm_out<<<dim3(32, 16), 256, 0, stream>>>(ctx16, W16 + 3 * (size_t)DD, bo, query, out);
}